// Round 1
// baseline (550.824 us; speedup 1.0000x reference)
//
#include <hip/hip_runtime.h>

#define NB   16
#define SQL  2048
#define SKL  2048
#define DKL  64
#define DVL  64
#define NE   (NB * SQL * DKL)   /* 2,097,152 elems per tensor */

typedef __attribute__((ext_vector_type(8))) short short8;
typedef __attribute__((ext_vector_type(4))) short s16x4;
typedef __attribute__((ext_vector_type(4))) float f32x4;

#define PST 56   // P LDS row stride (elems)

#define SCALE_LOG2E 0.1803368801111204f  /* (1/sqrt(64)) * log2(e) */
#define EXP2F(x) __builtin_amdgcn_exp2f(x)

__device__ __forceinline__ short f2bf(float x) {  // rne f32 -> bf16 bits
    unsigned u = __builtin_bit_cast(unsigned, x);
    u = (u + 0x7fffu + ((u >> 16) & 1u)) >> 16;
    return (short)u;
}
__device__ __forceinline__ float bf2f(short s) {
    return __builtin_bit_cast(float, ((unsigned)(unsigned short)s) << 16);
}

// ---------- prep: split Q,K into bf16 hi/lo ----------
__global__ __launch_bounds__(256)
void prep(const float* __restrict__ Q, const float* __restrict__ K,
          short* __restrict__ ws)
{
    short* qhi = ws;
    short* qlo = ws + (size_t)NE;
    short* khi = ws + (size_t)2 * NE;
    short* klo = ws + (size_t)3 * NE;

    size_t i4 = ((size_t)blockIdx.x * 256 + threadIdx.x) * 4;
    if (i4 >= NE) return;

    f32x4 q = *(const f32x4*)(Q + i4);
    f32x4 k = *(const f32x4*)(K + i4);
    s16x4 qh, ql, kh, kl;
    #pragma unroll
    for (int j = 0; j < 4; j++) {
        qh[j] = f2bf(q[j]);  ql[j] = f2bf(q[j] - bf2f(qh[j]));
        kh[j] = f2bf(k[j]);  kl[j] = f2bf(k[j] - bf2f(kh[j]));
    }
    *(s16x4*)(qhi + i4) = qh;
    *(s16x4*)(qlo + i4) = ql;
    *(s16x4*)(khi + i4) = kh;
    *(s16x4*)(klo + i4) = kl;
}

// ---------- vtrans: V fp32 [b][k][v] -> bf16 Vt [b][v][k] via LDS tile ----------
__global__ __launch_bounds__(256)
void vtrans(const float* __restrict__ V, short* __restrict__ vt)
{
    __shared__ short st[64][72];          // 64x64 tile, padded stride
    const int b  = blockIdx.x >> 5;       // 32 k-tiles per batch
    const int kt = blockIdx.x & 31;
    const int t  = threadIdx.x;

    const int kr = t >> 2;                // 0..63  (k row within tile)
    const int c0 = (t & 3) * 16;          // 0,16,32,48 (v col chunk)
    const float* vsrc = V + ((size_t)(b * SKL) + kt * 64 + kr) * DVL + c0;
    #pragma unroll
    for (int j = 0; j < 4; j++) {
        f32x4 x = *(const f32x4*)(vsrc + j * 4);
        #pragma unroll
        for (int i = 0; i < 4; i++) st[kr][c0 + j * 4 + i] = f2bf(x[i]);
    }
    __syncthreads();

    const int vr = t >> 2;                // v row of output
    const int k0 = (t & 3) * 16;          // k chunk
    short* dst = vt + (size_t)b * DVL * SKL + (size_t)vr * SKL + kt * 64 + k0;
    #pragma unroll
    for (int j = 0; j < 4; j++) {
        s16x4 o;
        #pragma unroll
        for (int m = 0; m < 4; m++) o[m] = st[k0 + j * 4 + m][vr];
        *(s16x4*)(dst + j * 4) = o;
    }
}

// s-tiles for 32 keys: s = Qhi*Khi + Qhi*Klo + Qlo*Khi  (split-bf16, ~fp32 accurate)
__device__ __forceinline__ void qk_tiles(const short* __restrict__ khi,
                                         const short* __restrict__ klo, int kb,
                                         int l15, int quad,
                                         short8 qa0h, short8 qa1h,
                                         short8 qa0l, short8 qa1l,
                                         f32x4& s0, f32x4& s1) {
    size_t o0 = (size_t)(kb + l15) * DKL + quad * 8;
    size_t o1 = (size_t)(kb + 16 + l15) * DKL + quad * 8;
    short8 h0l = *(const short8*)(khi + o0);
    short8 h0h = *(const short8*)(khi + o0 + 32);
    short8 h1l = *(const short8*)(khi + o1);
    short8 h1h = *(const short8*)(khi + o1 + 32);
    short8 l0l = *(const short8*)(klo + o0);
    short8 l0h = *(const short8*)(klo + o0 + 32);
    short8 l1l = *(const short8*)(klo + o1);
    short8 l1h = *(const short8*)(klo + o1 + 32);
    f32x4 z = {0.f, 0.f, 0.f, 0.f};
    s0 = __builtin_amdgcn_mfma_f32_16x16x32_bf16(qa0h, h0l, z, 0, 0, 0);
    s0 = __builtin_amdgcn_mfma_f32_16x16x32_bf16(qa1h, h0h, s0, 0, 0, 0);
    s0 = __builtin_amdgcn_mfma_f32_16x16x32_bf16(qa0h, l0l, s0, 0, 0, 0);
    s0 = __builtin_amdgcn_mfma_f32_16x16x32_bf16(qa1h, l0h, s0, 0, 0, 0);
    s0 = __builtin_amdgcn_mfma_f32_16x16x32_bf16(qa0l, h0l, s0, 0, 0, 0);
    s0 = __builtin_amdgcn_mfma_f32_16x16x32_bf16(qa1l, h0h, s0, 0, 0, 0);
    s1 = __builtin_amdgcn_mfma_f32_16x16x32_bf16(qa0h, h1l, z, 0, 0, 0);
    s1 = __builtin_amdgcn_mfma_f32_16x16x32_bf16(qa1h, h1h, s1, 0, 0, 0);
    s1 = __builtin_amdgcn_mfma_f32_16x16x32_bf16(qa0h, l1l, s1, 0, 0, 0);
    s1 = __builtin_amdgcn_mfma_f32_16x16x32_bf16(qa1h, l1h, s1, 0, 0, 0);
    s1 = __builtin_amdgcn_mfma_f32_16x16x32_bf16(qa0l, h1l, s1, 0, 0, 0);
    s1 = __builtin_amdgcn_mfma_f32_16x16x32_bf16(qa1l, h1h, s1, 0, 0, 0);
}

// Block = one 16-row q-tile, 4 waves each owning a 512-key quarter (K-split).
// No per-iteration barriers: V comes pre-transposed from global (L2-hot),
// P roundtrip is per-wave-private LDS (lgkmcnt only).
__global__ __launch_bounds__(256, 4)
void attn_fwd(const short* __restrict__ ws, const int* __restrict__ mask,
              float* __restrict__ out, float* __restrict__ attn)
{
    __shared__ __align__(16) char smem[16384 + 256];
    short* s_p   = (short*)smem;                 // 4 waves x 16 x PST shorts (7 KB)
    f32x4* s_acc = (f32x4*)smem;                 // 4 waves x 64 lanes x 4 tiles (16 KB, aliased)
    float* s_red = (float*)(smem + 16384);       // 4 waves x 16 row-sums

    const int tid  = threadIdx.x;
    const int w    = tid >> 6;                   // wave = k-quarter
    const int lane = tid & 63;
    const int l15  = tid & 15;
    const int quad = (tid & 63) >> 4;

    // bijective XCD swizzle: 2048 blocks, 256-block chunks per XCD (= 2 batches)
    const int bid = blockIdx.x;
    const int swz = (bid & 7) * ((NB * SQL / 16) >> 3) + (bid >> 3);
    const int b     = swz >> 7;
    const int qbase = (swz & 127) * 16;

    const int k0 = w * (SKL / 4);
    const int k1 = k0 + SKL / 4;

    const short* qhi = ws + (size_t)(b * SQL + qbase) * DKL;
    const short* qlo = qhi + (size_t)NE;
    const short* khi = ws + (size_t)2 * NE + (size_t)b * SKL * DKL;
    const short* klo = khi + (size_t)NE;
    const short* vtg = ws + (size_t)4 * NE + (size_t)b * DVL * SKL;
    const int*   mk  = mask + b * SKL;

    short8 qa0h = *(const short8*)(qhi + (size_t)l15 * DKL + quad * 8);
    short8 qa1h = *(const short8*)(qhi + (size_t)l15 * DKL + 32 + quad * 8);
    short8 qa0l = *(const short8*)(qlo + (size_t)l15 * DKL + quad * 8);
    short8 qa1l = *(const short8*)(qlo + (size_t)l15 * DKL + 32 + quad * 8);

    // ---------- sweep 1: partial denominators over this wave's quarter ----------
    float lsum[4] = {0.f, 0.f, 0.f, 0.f};
    for (int kb = k0; kb < k1; kb += 32) {
        f32x4 s0, s1;
        qk_tiles(khi, klo, kb, l15, quad, qa0h, qa1h, qa0l, qa1l, s0, s1);
        float bias0 = mk[kb + l15]      ? 0.0f : -1e9f;
        float bias1 = mk[kb + 16 + l15] ? 0.0f : -1e9f;
        #pragma unroll
        for (int r = 0; r < 4; r++) {
            lsum[r] += EXP2F(fmaf(s0[r], SCALE_LOG2E, bias0));
            lsum[r] += EXP2F(fmaf(s1[r], SCALE_LOG2E, bias1));
        }
    }
    #pragma unroll
    for (int off = 1; off <= 8; off <<= 1) {
        #pragma unroll
        for (int r = 0; r < 4; r++)
            lsum[r] += __shfl_xor(lsum[r], off, 64);
    }
    if (l15 == 0) {
        #pragma unroll
        for (int r = 0; r < 4; r++) s_red[w * 16 + quad * 4 + r] = lsum[r];
    }
    __syncthreads();
    float inv_l[4];
    #pragma unroll
    for (int r = 0; r < 4; r++) {
        float t_ = s_red[quad * 4 + r] + s_red[16 + quad * 4 + r]
                 + s_red[32 + quad * 4 + r] + s_red[48 + quad * 4 + r];
        inv_l[r] = 1.0f / t_;
    }

    // ---------- sweep 2: attn write + partial P·V ----------
    f32x4 acc[4];
    #pragma unroll
    for (int vt = 0; vt < 4; vt++) { f32x4 z = {0.f,0.f,0.f,0.f}; acc[vt] = z; }

    short* pw = s_p + w * 16 * PST;

    for (int kb = k0; kb < k1; kb += 32) {
        // V fragments: direct coalesced loads from pre-transposed Vt (L2-hot)
        const short* vrow = vtg + kb + quad * 8;
        short8 bv0 = *(const short8*)(vrow + (size_t)(0 * 16 + l15) * SKL);
        short8 bv1 = *(const short8*)(vrow + (size_t)(1 * 16 + l15) * SKL);
        short8 bv2 = *(const short8*)(vrow + (size_t)(2 * 16 + l15) * SKL);
        short8 bv3 = *(const short8*)(vrow + (size_t)(3 * 16 + l15) * SKL);
        float bias0 = mk[kb + l15]      ? 0.0f : -1e9f;
        float bias1 = mk[kb + 16 + l15] ? 0.0f : -1e9f;

        f32x4 s0, s1;
        qk_tiles(khi, klo, kb, l15, quad, qa0h, qa1h, qa0l, qa1l, s0, s1);

        const size_t arow = (size_t)(b * SQL + qbase + quad * 4) * SKL + kb;
        #pragma unroll
        for (int r = 0; r < 4; r++) {
            float p0 = EXP2F(fmaf(s0[r], SCALE_LOG2E, bias0)) * inv_l[r];
            float p1 = EXP2F(fmaf(s1[r], SCALE_LOG2E, bias1)) * inv_l[r];
            __builtin_nontemporal_store(p0, &attn[arow + (size_t)r * SKL + l15]);
            __builtin_nontemporal_store(p1, &attn[arow + (size_t)r * SKL + 16 + l15]);
            pw[(quad * 4 + r) * PST + l15]      = f2bf(p0);
            pw[(quad * 4 + r) * PST + 16 + l15] = f2bf(p1);
        }

        short8 pa = *(const short8*)(pw + l15 * PST + quad * 8);
        acc[0] = __builtin_amdgcn_mfma_f32_16x16x32_bf16(pa, bv0, acc[0], 0, 0, 0);
        acc[1] = __builtin_amdgcn_mfma_f32_16x16x32_bf16(pa, bv1, acc[1], 0, 0, 0);
        acc[2] = __builtin_amdgcn_mfma_f32_16x16x32_bf16(pa, bv2, acc[2], 0, 0, 0);
        acc[3] = __builtin_amdgcn_mfma_f32_16x16x32_bf16(pa, bv3, acc[3], 0, 0, 0);
    }

    // ---------- combine partial P·V across the 4 k-quarter waves ----------
    __syncthreads();   // everyone done with their private s_p before aliasing
    #pragma unroll
    for (int vt = 0; vt < 4; vt++) s_acc[(w * 64 + lane) * 4 + vt] = acc[vt];
    __syncthreads();

    f32x4 t_ = s_acc[(0 * 64 + lane) * 4 + w];
    #pragma unroll
    for (int wp = 1; wp < 4; wp++) {
        f32x4 u = s_acc[(wp * 64 + lane) * 4 + w];
        #pragma unroll
        for (int r = 0; r < 4; r++) t_[r] += u[r];
    }
    #pragma unroll
    for (int r = 0; r < 4; r++)
        out[(size_t)(b * SQL + qbase + quad * 4 + r) * DVL + w * 16 + l15] = t_[r];
}

extern "C" void kernel_launch(void* const* d_in, const int* in_sizes, int n_in,
                              void* d_out, int out_size, void* d_ws, size_t ws_size,
                              hipStream_t stream) {
    const float* Q    = (const float*)d_in[0];
    const float* K    = (const float*)d_in[1];
    const float* V    = (const float*)d_in[2];
    const int*   mask = (const int*)d_in[3];
    float* out  = (float*)d_out;
    float* attn = out + (size_t)NB * SQL * DVL;  // tuple order: (output, attn)
    short* ws   = (short*)d_ws;                  // 5*NE shorts = 20 MB

    prep<<<dim3(NE / (256 * 4)), dim3(256), 0, stream>>>(Q, K, ws);
    vtrans<<<dim3(NB * (SKL / 64)), dim3(256), 0, stream>>>(V, ws + (size_t)4 * NE);
    attn_fwd<<<dim3(NB * (SQL / 16)), dim3(256), 0, stream>>>(ws, mask, out, attn);
}